// Round 11
// baseline (149.067 us; speedup 1.0000x reference)
//
#include <hip/hip_runtime.h>
#include <hip/hip_bf16.h>

typedef __attribute__((ext_vector_type(8))) short bf16x8;
typedef __attribute__((ext_vector_type(4))) short bf16x4;
typedef __attribute__((ext_vector_type(4))) float f32x4;
typedef __attribute__((ext_vector_type(2))) unsigned int u32x2;

__device__ __forceinline__ void gload_lds16(const void* g, void* l) {
    __builtin_amdgcn_global_load_lds(
        (const __attribute__((address_space(1))) unsigned int*)g,
        (__attribute__((address_space(3))) unsigned int*)l, 16, 0, 0);
}

__device__ __forceinline__ unsigned int pk2(float x, float y) {
    union { __hip_bfloat16 h[2]; unsigned int u; } z;
    z.h[0] = __float2bfloat16(x); z.h[1] = __float2bfloat16(y);
    return z.u;
}

// 16x16x16 bf16 MFMA (HW-verified round 6)
__device__ __forceinline__ f32x4 mfma_16x16x16(bf16x4 a, bf16x4 b, f32x4 c) {
#if __has_builtin(__builtin_amdgcn_mfma_f32_16x16x16bf16_1k)
    return __builtin_amdgcn_mfma_f32_16x16x16bf16_1k(a, b, c, 0, 0, 0);
#else
    f32x4 d = c;
    asm volatile("v_mfma_f32_16x16x16_bf16 %0, %1, %2, %0" : "+v"(d) : "v"(a), "v"(b));
    return d;
#endif
}

#define BARRIER() asm volatile("s_barrier" ::: "memory")
#define LGKM0()   asm volatile("s_waitcnt lgkmcnt(0)" ::: "memory")
#define VM2()     asm volatile("s_waitcnt vmcnt(2)" ::: "memory")
#define VM0()     asm volatile("s_waitcnt vmcnt(0)" ::: "memory")

// ---------------- fp32 -> bf16 elementwise convert (8 elems/thread) ----------------
__global__ void k_cvt_bf16(const float* __restrict__ x, __hip_bfloat16* __restrict__ o, int n8) {
    int i = blockIdx.x * 256 + threadIdx.x;
    if (i >= n8) return;
    const float4* xp = (const float4*)(x + (size_t)i * 8);
    float4 a = xp[0], b = xp[1];
    union { __hip_bfloat16 h[8]; uint4 u; } tu;
    tu.h[0] = __float2bfloat16(a.x); tu.h[1] = __float2bfloat16(a.y);
    tu.h[2] = __float2bfloat16(a.z); tu.h[3] = __float2bfloat16(a.w);
    tu.h[4] = __float2bfloat16(b.x); tu.h[5] = __float2bfloat16(b.y);
    tu.h[6] = __float2bfloat16(b.z); tu.h[7] = __float2bfloat16(b.w);
    *(uint4*)(o + (size_t)i * 8) = tu.u;
}

// ---------------- transpose fp32 [K][N] -> bf16 [N][K]; z selects one of 3 sources ----------------
__global__ void k_tr3(const float* __restrict__ s0, const float* __restrict__ s1,
                      const float* __restrict__ s2, __hip_bfloat16* __restrict__ dst,
                      int K, int N) {
    __shared__ float tile[32][33];
    const float* src = (blockIdx.z == 0) ? s0 : ((blockIdx.z == 1) ? s1 : s2);
    __hip_bfloat16* d = dst + (size_t)blockIdx.z * N * K;
    int n0 = blockIdx.x * 32, k0 = blockIdx.y * 32;
    int tx = threadIdx.x & 31, ty = threadIdx.x >> 5;
#pragma unroll
    for (int i = 0; i < 4; i++)
        tile[ty + i * 8][tx] = src[(size_t)(k0 + ty + i * 8) * N + n0 + tx];
    __syncthreads();
#pragma unroll
    for (int i = 0; i < 4; i++)
        d[(size_t)(n0 + ty + i * 8) * K + k0 + tx] = __float2bfloat16(tile[tx][ty + i * 8]);
}

__global__ void k_tr(const float* __restrict__ src, __hip_bfloat16* __restrict__ dst, int K, int N) {
    __shared__ float tile[32][33];
    int n0 = blockIdx.x * 32, k0 = blockIdx.y * 32;
    int tx = threadIdx.x & 31, ty = threadIdx.x >> 5;
#pragma unroll
    for (int i = 0; i < 4; i++)
        tile[ty + i * 8][tx] = src[(size_t)(k0 + ty + i * 8) * N + n0 + tx];
    __syncthreads();
#pragma unroll
    for (int i = 0; i < 4; i++)
        dst[(size_t)(n0 + ty + i * 8) * K + k0 + tx] = __float2bfloat16(tile[tx][ty + i * 8]);
}

#define QSCALE 0.18033688011111204f  /* (1/8) * log2(e) */

// ================= 256x256 8-phase GEMM (QKV) =================
// 8 waves (2m x 4n), BK=64, 2 K-tiles/iter, LDS 128KB (2dbuf x [256][64] x A,B, XOR-swizzled).
// Counted vmcnt(2) at phases 4/8 only (never 0 in steady state); raw s_barrier (no drain).
// Stage ledger (iteration i, tiles T0=2i buf0 / T1=2i+1 buf1):
//   ph1: A1(T1)  ph2: B0(T1)  ph3: B1(T1)          [buf1 halves freed by prev iter ph7/ph8]
//   ph4: A0(T0+2), vmcnt(2) -> T1 fully landed      [buf0.A* freed after ph3]
//   ph5: A1(T0+2) ph6: B0(T0+2) ph7: B1(T0+2)       [buf0.B* freed after ph4]
//   ph8: A0(T1+2), vmcnt(2) -> T0+2 fully landed    [buf1.A0 freed after ph7]
__device__ __forceinline__ void read_af(const __hip_bfloat16* base, int wm, int mh, int r16,
                                        int kg, int swr, bf16x8 af[4][2]) {
#pragma unroll
    for (int mf = 0; mf < 4; ++mf)
#pragma unroll
        for (int kc = 0; kc < 2; ++kc) {
            const int row = wm * 128 + (mh * 4 + mf) * 16 + r16;
            af[mf][kc] = *(const bf16x8*)(base + row * 64 + ((kc * 32 + kg * 8) ^ swr));
        }
}
__device__ __forceinline__ void read_bf(const __hip_bfloat16* base, int wn, int nh, int r16,
                                        int kg, int swr, bf16x8 bfr[2][2]) {
#pragma unroll
    for (int nf = 0; nf < 2; ++nf)
#pragma unroll
        for (int kc = 0; kc < 2; ++kc) {
            const int row = wn * 64 + (nh * 2 + nf) * 16 + r16;
            bfr[nf][kc] = *(const bf16x8*)(base + row * 64 + ((kc * 32 + kg * 8) ^ swr));
        }
}
__device__ __forceinline__ void mfma_q(f32x4 (&acc)[8][4], bf16x8 af[4][2], bf16x8 bfr[2][2],
                                       int mh, int nh) {
#pragma unroll
    for (int mf = 0; mf < 4; ++mf)
#pragma unroll
        for (int nf = 0; nf < 2; ++nf)
#pragma unroll
            for (int kc = 0; kc < 2; ++kc)
                acc[mh * 4 + mf][nh * 2 + nf] = __builtin_amdgcn_mfma_f32_16x16x32_bf16(
                    af[mf][kc], bfr[nf][kc], acc[mh * 4 + mf][nh * 2 + nf], 0, 0, 0);
}

__global__ __launch_bounds__(512, 2) void k_gemm8(
    const __hip_bfloat16* __restrict__ A, const __hip_bfloat16* __restrict__ Bt, int K,
    const float* __restrict__ b0, const float* __restrict__ b1, const float* __restrict__ b2,
    __hip_bfloat16* __restrict__ qb, __hip_bfloat16* __restrict__ kb, __hip_bfloat16* __restrict__ vb)
{
    __shared__ __align__(16) __hip_bfloat16 Al[2][256 * 64];
    __shared__ __align__(16) __hip_bfloat16 Bl[2][256 * 64];
    const int t = threadIdx.x;
    const int lane = t & 63, wid = t >> 6;
    const int r16 = lane & 15, kg = lane >> 4;
    const int wm = wid >> 2, wn = wid & 3;
    const int m0 = blockIdx.x * 256, n0 = blockIdx.y * 256;
    const int swr = (r16 & 7) << 3;

    // staging geometry: half-tile = [128 rows][64 cols]; 512 thr x 2 chunks x 16B
    const int ci0 = t, ci1 = 512 + t;
    const int sr0 = ci0 >> 3, sc0 = ((ci0 & 7) * 8) ^ ((sr0 & 7) << 3);
    const int sr1 = ci1 >> 3, sc1 = ((ci1 & 7) * 8) ^ ((sr1 & 7) << 3);

    auto stA = [&](int b, int h, int kt) {
        gload_lds16(A + (size_t)(m0 + h * 128 + sr0) * K + kt * 64 + sc0, &Al[b][h * 8192 + ci0 * 8]);
        gload_lds16(A + (size_t)(m0 + h * 128 + sr1) * K + kt * 64 + sc1, &Al[b][h * 8192 + ci1 * 8]);
    };
    auto stB = [&](int b, int h, int kt) {
        gload_lds16(Bt + (size_t)(n0 + h * 128 + sr0) * K + kt * 64 + sc0, &Bl[b][h * 8192 + ci0 * 8]);
        gload_lds16(Bt + (size_t)(n0 + h * 128 + sr1) * K + kt * 64 + sc1, &Bl[b][h * 8192 + ci1 * 8]);
    };

    f32x4 acc[8][4] = {};
    const int nkt = K >> 6, niter = nkt >> 1;

    // prologue: tile 0 complete + A0(tile 1); wait tile 0 (leave A0(t1) in flight)
    stA(0, 0, 0); stA(0, 1, 0); stB(0, 0, 0); stB(0, 1, 0);
    stA(1, 0, 1);
    VM2(); BARRIER();

    for (int it = 0; it < niter; ++it) {
        const int t1 = 2 * it + 1;
        const bool last = (it == niter - 1);
        bf16x8 af[4][2], bfr[2][2];
        // ---------- K-tile 2i in buf0 : phases 1-4 ----------
        // ph1 (Q00)
        read_af(Al[0], wm, 0, r16, kg, swr, af);
        read_bf(Bl[0], wn, 0, r16, kg, swr, bfr);
        stA(1, 1, t1);
        BARRIER(); LGKM0();
        __builtin_amdgcn_s_setprio(1); mfma_q(acc, af, bfr, 0, 0); __builtin_amdgcn_s_setprio(0);
        BARRIER();
        // ph2 (Q01)
        read_bf(Bl[0], wn, 1, r16, kg, swr, bfr);
        stB(1, 0, t1);
        BARRIER(); LGKM0();
        __builtin_amdgcn_s_setprio(1); mfma_q(acc, af, bfr, 0, 1); __builtin_amdgcn_s_setprio(0);
        BARRIER();
        // ph3 (Q10)
        read_af(Al[0], wm, 1, r16, kg, swr, af);
        read_bf(Bl[0], wn, 0, r16, kg, swr, bfr);
        stB(1, 1, t1);
        BARRIER(); LGKM0();
        __builtin_amdgcn_s_setprio(1); mfma_q(acc, af, bfr, 1, 0); __builtin_amdgcn_s_setprio(0);
        BARRIER();
        // ph4 (Q11) + vmcnt checkpoint (T1 must be fully landed before ph5 reads)
        read_bf(Bl[0], wn, 1, r16, kg, swr, bfr);
        if (!last) stA(0, 0, t1 + 1);
        BARRIER(); LGKM0();
        __builtin_amdgcn_s_setprio(1); mfma_q(acc, af, bfr, 1, 1); __builtin_amdgcn_s_setprio(0);
        if (last) { VM0(); } else { VM2(); }
        BARRIER();
        // ---------- K-tile 2i+1 in buf1 : phases 5-8 ----------
        // ph5 (Q00)
        read_af(Al[1], wm, 0, r16, kg, swr, af);
        read_bf(Bl[1], wn, 0, r16, kg, swr, bfr);
        if (!last) stA(0, 1, t1 + 1);
        BARRIER(); LGKM0();
        __builtin_amdgcn_s_setprio(1); mfma_q(acc, af, bfr, 0, 0); __builtin_amdgcn_s_setprio(0);
        BARRIER();
        // ph6 (Q01)
        read_bf(Bl[1], wn, 1, r16, kg, swr, bfr);
        if (!last) stB(0, 0, t1 + 1);
        BARRIER(); LGKM0();
        __builtin_amdgcn_s_setprio(1); mfma_q(acc, af, bfr, 0, 1); __builtin_amdgcn_s_setprio(0);
        BARRIER();
        // ph7 (Q10)
        read_af(Al[1], wm, 1, r16, kg, swr, af);
        read_bf(Bl[1], wn, 0, r16, kg, swr, bfr);
        if (!last) stB(0, 1, t1 + 1);
        BARRIER(); LGKM0();
        __builtin_amdgcn_s_setprio(1); mfma_q(acc, af, bfr, 1, 0); __builtin_amdgcn_s_setprio(0);
        BARRIER();
        // ph8 (Q11) + vmcnt checkpoint (T0+2 must be fully landed before next ph1)
        read_bf(Bl[1], wn, 1, r16, kg, swr, bfr);
        if (!last) stA(1, 0, t1 + 2);
        BARRIER(); LGKM0();
        __builtin_amdgcn_s_setprio(1); mfma_q(acc, af, bfr, 1, 1); __builtin_amdgcn_s_setprio(0);
        if (!last) { VM2(); }
        BARRIER();
    }

    // ---------------- epilogue ----------------
    if (n0 >= 2048) {
        // V path: transpose via LDS halves (wm0 -> Al flat, wm1 -> Bl flat), coalesced 16B stores
        __hip_bfloat16* Alf = &Al[0][0];
        __hip_bfloat16* Blf = &Bl[0][0];
        __syncthreads();
        __hip_bfloat16* dst = wm ? Blf : Alf;
#pragma unroll
        for (int mf = 0; mf < 8; ++mf) {
#pragma unroll
            for (int nf = 0; nf < 4; ++nf) {
                const int nl = wn * 64 + nf * 16 + r16;
                const int mp = mf * 16 + kg * 4;
                const float bias = b2[n0 - 2048 + nl];
                u32x2 pk;
                pk[0] = pk2(acc[mf][nf][0] + bias, acc[mf][nf][1] + bias);
                pk[1] = pk2(acc[mf][nf][2] + bias, acc[mf][nf][3] + bias);
                *(u32x2*)(dst + nl * 128 + (mp ^ ((nl & 7) << 3))) = pk;
            }
        }
        __syncthreads();
#pragma unroll
        for (int h = 0; h < 2; ++h) {
            const __hip_bfloat16* src = h ? Blf : Alf;
#pragma unroll
            for (int pass = 0; pass < 8; ++pass) {
                const int ci = pass * 512 + t;
                const int nl = ci >> 4;
                const int ms = (ci & 15) * 8;
                bf16x8 v = *(const bf16x8*)(src + nl * 128 + (ms ^ ((nl & 7) << 3)));
                const int r = n0 - 2048 + nl;
                const int hh = r >> 6, dd = r & 63;
                const int m = m0 + h * 128 + ms;
                const int bb = m >> 11, tt = m & 2047;
                *(bf16x8*)(vb + ((size_t)(bb * 16 + hh) * 64 + dd) * 2048 + tt) = v;
            }
        }
        return;
    }
    // Q / K path: scalar scatter (32B-contiguous per 16 lanes)
#pragma unroll
    for (int mf = 0; mf < 8; ++mf) {
#pragma unroll
        for (int nf = 0; nf < 4; ++nf) {
#pragma unroll
            for (int j = 0; j < 4; ++j) {
                const int m = m0 + wm * 128 + mf * 16 + kg * 4 + j;
                const int n = n0 + wn * 64 + nf * 16 + r16;
                const int r = n & 1023;
                const int hh = r >> 6, dd = r & 63;
                const int bb = m >> 11, tt = m & 2047;
                float val = acc[mf][nf][j];
                if (n0 < 1024) {
                    val = (val + b0[r]) * QSCALE;
                    qb[((size_t)(bb * 16 + hh) * 2048 + tt) * 64 + dd] = __float2bfloat16(val);
                } else {
                    val += b1[r];
                    kb[((size_t)(bb * 16 + hh) * 2048 + tt) * 64 + dd] = __float2bfloat16(val);
                }
            }
        }
    }
}

// ---------------- proj GEMM (proven 128x128, natural 2D grid) ----------------
__global__ __launch_bounds__(256, 2) void k_gemmP(
    const __hip_bfloat16* __restrict__ A, const __hip_bfloat16* __restrict__ Bt,
    int N, int K, const float* __restrict__ bias, float* __restrict__ outp)
{
    __shared__ __align__(16) __hip_bfloat16 As[128 * 64];
    __shared__ __align__(16) __hip_bfloat16 Bs[128 * 64];
    const int t = threadIdx.x;
    const int lane = t & 63, w = t >> 6;
    const int wr = w >> 1, wc = w & 1;
    const int r16 = lane & 15, kg = lane >> 4;
    const int m0 = blockIdx.x * 128, n0 = blockIdx.y * 128;
    f32x4 acc[4][4] = {};
    const int ksteps = K >> 6;
    for (int kt = 0; kt < ksteps; ++kt) {
        if (kt) __syncthreads();
        const int ks = kt * 64;
#pragma unroll
        for (int i = 0; i < 4; i++) {
            int ci = i * 256 + t;
            int row = ci >> 3, kc = (ci & 7) * 8;
            gload_lds16(A + (size_t)(m0 + row) * K + ks + kc, As + ci * 8);
        }
#pragma unroll
        for (int i = 0; i < 4; i++) {
            int ci = i * 256 + t;
            int row = ci >> 3, kc = (ci & 7) * 8;
            gload_lds16(Bt + (size_t)(n0 + row) * K + ks + kc, Bs + ci * 8);
        }
        __syncthreads();
#pragma unroll
        for (int c = 0; c < 2; c++) {
            bf16x8 af[4], bfr[4];
#pragma unroll
            for (int mi = 0; mi < 4; mi++)
                af[mi] = *(const bf16x8*)(As + (wr * 64 + mi * 16 + r16) * 64 + c * 32 + kg * 8);
#pragma unroll
            for (int ni = 0; ni < 4; ni++)
                bfr[ni] = *(const bf16x8*)(Bs + (wc * 64 + ni * 16 + r16) * 64 + c * 32 + kg * 8);
#pragma unroll
            for (int mi = 0; mi < 4; mi++)
#pragma unroll
                for (int ni = 0; ni < 4; ni++)
                    acc[mi][ni] = __builtin_amdgcn_mfma_f32_16x16x32_bf16(af[mi], bfr[ni], acc[mi][ni], 0, 0, 0);
        }
    }
#pragma unroll
    for (int mi = 0; mi < 4; mi++)
#pragma unroll
        for (int ni = 0; ni < 4; ni++)
#pragma unroll
            for (int j = 0; j < 4; j++) {
                int m = m0 + wr * 64 + mi * 16 + kg * 4 + j;
                int n = n0 + wc * 64 + ni * 16 + r16;
                outp[(size_t)m * N + n] = acc[mi][ni][j] + bias[n];
            }
}

// ---------------- flash attention (round-10 proven): v6 core + bh->XCD remap ----------------
__global__ __launch_bounds__(256, 4) void k_attn(
    const __hip_bfloat16* __restrict__ qbuf,
    const __hip_bfloat16* __restrict__ kbuf,
    const __hip_bfloat16* __restrict__ vtbuf,
    __hip_bfloat16* __restrict__ y)
{
    __shared__ __align__(16) __hip_bfloat16 Kl[2][64 * 64];
    __shared__ __align__(16) __hip_bfloat16 Vl[2][64 * 64];
    const int t = threadIdx.x, lane = t & 63, w = t >> 6;
    const int r16 = lane & 15, kg = lane >> 4;
    const int g = blockIdx.x;
    const int xcd = g & 7, idx = g >> 3;
    const int j4 = idx >> 5, rr = idx & 31;
    const int bh = xcd * 4 + j4;
    const int qt = (j4 & 1) ? rr : 31 - rr;
    const int swr = (r16 & 7) << 3;
    const int q0 = qt * 64 + w * 16;
    const __hip_bfloat16* qp = qbuf + ((size_t)bh * 2048 + q0) * 64;
    bf16x8 qf0 = *(const bf16x8*)(qp + r16 * 64 + kg * 8);
    bf16x8 qf1 = *(const bf16x8*)(qp + r16 * 64 + 32 + kg * 8);
    f32x4 O[4] = {};
    float m_s = -3.0e38f, l_s = 0.f;
    const __hip_bfloat16* kb = kbuf + (size_t)bh * 2048 * 64;
    const __hip_bfloat16* vb = vtbuf + (size_t)bh * 64 * 2048;

    const int ci0 = t, ci1 = 256 + t;
    const int kr0 = ci0 >> 3, sc0 = ((ci0 & 7) * 8) ^ ((kr0 & 7) << 3);
    const int kr1 = ci1 >> 3, sc1 = ((ci1 & 7) * 8) ^ ((kr1 & 7) << 3);

    gload_lds16(kb + (size_t)kr0 * 64 + sc0, &Kl[0][ci0 * 8]);
    gload_lds16(kb + (size_t)kr1 * 64 + sc1, &Kl[0][ci1 * 8]);
    gload_lds16(vb + (size_t)kr0 * 2048 + sc0, &Vl[0][ci0 * 8]);
    gload_lds16(vb + (size_t)kr1 * 2048 + sc1, &Vl[0][ci1 * 8]);
    __syncthreads();

    for (int kt = 0; kt <= qt; ++kt) {
        const int cur = kt & 1;
        if (kt < qt) {
            const int kn = kt + 1;
            gload_lds16(kb + (size_t)kn * 4096 + (size_t)kr0 * 64 + sc0, &Kl[cur ^ 1][ci0 * 8]);
            gload_lds16(kb + (size_t)kn * 4096 + (size_t)kr1 * 64 + sc1, &Kl[cur ^ 1][ci1 * 8]);
            gload_lds16(vb + (size_t)kr0 * 2048 + kn * 64 + sc0, &Vl[cur ^ 1][ci0 * 8]);
            gload_lds16(vb + (size_t)kr1 * 2048 + kn * 64 + sc1, &Vl[cur ^ 1][ci1 * 8]);
        }
        const int kbase = kt * 64;
        {
            const __hip_bfloat16* Klb = Kl[cur];
            const __hip_bfloat16* Vlb = Vl[cur];
            f32x4 S[4];
            __builtin_amdgcn_s_setprio(1);
#pragma unroll
            for (int ct = 0; ct < 4; ct++) {
                f32x4 s = {};
                const int r = ct * 16 + r16;
                bf16x8 kf0 = *(const bf16x8*)(Klb + r * 64 + ((kg * 8) ^ swr));
                s = __builtin_amdgcn_mfma_f32_16x16x32_bf16(kf0, qf0, s, 0, 0, 0);
                bf16x8 kf1 = *(const bf16x8*)(Klb + r * 64 + ((32 + kg * 8) ^ swr));
                s = __builtin_amdgcn_mfma_f32_16x16x32_bf16(kf1, qf1, s, 0, 0, 0);
                S[ct] = s;
            }
            __builtin_amdgcn_s_setprio(0);
            if (kbase + 63 > q0) {
#pragma unroll
                for (int ct = 0; ct < 4; ct++)
#pragma unroll
                    for (int j = 0; j < 4; j++)
                        if (kbase + ct * 16 + kg * 4 + j > q0 + r16) S[ct][j] = -3.0e38f;
            }
            float rmax = S[0][0];
#pragma unroll
            for (int ct = 0; ct < 4; ct++)
#pragma unroll
                for (int j = 0; j < 4; j++) rmax = fmaxf(rmax, S[ct][j]);
            rmax = fmaxf(rmax, __shfl_xor(rmax, 16));
            rmax = fmaxf(rmax, __shfl_xor(rmax, 32));
            if (__any(rmax > m_s + 8.0f)) {
                const float mn = fmaxf(m_s, rmax);
                const float al = exp2f(m_s - mn);
                m_s = mn;
                l_s *= al;
#pragma unroll
                for (int j = 0; j < 4; j++) {
                    const float aj = __shfl(al, kg * 4 + j);
#pragma unroll
                    for (int ot = 0; ot < 4; ot++) O[ot][j] *= aj;
                }
            }
            float rsum = 0.f;
#pragma unroll
            for (int ct = 0; ct < 4; ct++)
#pragma unroll
                for (int j = 0; j < 4; j++) { S[ct][j] = exp2f(S[ct][j] - m_s); rsum += S[ct][j]; }
            rsum += __shfl_xor(rsum, 16);
            rsum += __shfl_xor(rsum, 32);
            l_s += rsum;
            bf16x4 pa[4];
#pragma unroll
            for (int ct = 0; ct < 4; ct++) {
                union { __hip_bfloat16 h[4]; bf16x4 v; } pk;
                pk.h[0] = __float2bfloat16(S[ct][0]);
                pk.h[1] = __float2bfloat16(S[ct][1]);
                pk.h[2] = __float2bfloat16(S[ct][2]);
                pk.h[3] = __float2bfloat16(S[ct][3]);
                pa[ct] = pk.v;
            }
            __builtin_amdgcn_s_setprio(1);
#pragma unroll
            for (int ot = 0; ot < 4; ot++) {
                const int vrow = ot * 16 + r16;
#pragma unroll
                for (int ct = 0; ct < 4; ct++) {
                    bf16x4 vf = *(const bf16x4*)(Vlb + vrow * 64 + ((ct * 16 + kg * 4) ^ ((vrow & 7) << 3)));
                    O[ot] = mfma_16x16x16(pa[ct], vf, O[ot]);
                }
            }
            __builtin_amdgcn_s_setprio(0);
        }
        __syncthreads();
    }
    const int b = bh >> 4, h = bh & 15;
    const float linv = 1.0f / l_s;
#pragma unroll
    for (int j = 0; j < 4; j++) {
        const float iv = __shfl(linv, kg * 4 + j);
        const int qq = q0 + kg * 4 + j;
#pragma unroll
        for (int ot = 0; ot < 4; ot++)
            y[((size_t)b * 2048 + qq) * 1024 + h * 64 + ot * 16 + r16] = __float2bfloat16(O[ot][j] * iv);
    }
}

extern "C" void kernel_launch(void* const* d_in, const int* in_sizes, int n_in,
                              void* d_out, int out_size, void* d_ws, size_t ws_size,
                              hipStream_t stream) {
    const float* xp = (const float*)d_in[0];
    const float* Wq = (const float*)d_in[1];
    const float* bq = (const float*)d_in[2];
    const float* Wk = (const float*)d_in[3];
    const float* bk = (const float*)d_in[4];
    const float* Wv = (const float*)d_in[5];
    const float* bv = (const float*)d_in[6];
    const float* Wp = (const float*)d_in[7];
    const float* bp = (const float*)d_in[8];
    float* out = (float*)d_out;

    char* ws = (char*)d_ws;
    __hip_bfloat16* xb     = (__hip_bfloat16*)(ws);                  //  4096*1152 bf16
    __hip_bfloat16* Wqkv_t = (__hip_bfloat16*)(ws + 9437184);        //  3072*1152 bf16 (B^T)
    __hip_bfloat16* Wp_t   = (__hip_bfloat16*)(ws + 16515072);       //  1024*1024 bf16 (B^T)
    __hip_bfloat16* qb     = (__hip_bfloat16*)(ws + 18612224);       //  [32][2048][64]
    __hip_bfloat16* kbv    = (__hip_bfloat16*)(ws + 27000832);       //  [32][2048][64]
    __hip_bfloat16* vtb    = (__hip_bfloat16*)(ws + 35389440);       //  [32][64][2048] (V^T)
    __hip_bfloat16* yb     = (__hip_bfloat16*)(ws + 43778048);       //  [4096][1024]

    k_cvt_bf16<<<2304, 256, 0, stream>>>(xp, xb, 589824);
    dim3 trg3(1024 / 32, 1152 / 32, 3);
    k_tr3<<<trg3, 256, 0, stream>>>(Wq, Wk, Wv, Wqkv_t, 1152, 1024);
    dim3 trg2(1024 / 32, 1024 / 32);
    k_tr<<<trg2, 256, 0, stream>>>(Wp, Wp_t, 1024, 1024);

    // QKV: 256x256 8-phase, 16 x 12 = 192 blocks (all co-resident)
    dim3 g8(4096 / 256, 3072 / 256);
    k_gemm8<<<g8, 512, 0, stream>>>(xb, Wqkv_t, 1152, bq, bk, bv, qb, kbv, vtb);
    k_attn<<<1024, 256, 0, stream>>>(qb, kbv, vtb, yb);
    dim3 gp(4096 / 128, 1024 / 128);
    k_gemmP<<<gp, 256, 0, stream>>>(yb, Wp_t, 1024, 1024, bp, out);
}

// Round 12
// 131.805 us; speedup vs baseline: 1.1310x; 1.1310x over previous
//
#include <hip/hip_runtime.h>
#include <hip/hip_bf16.h>

typedef __attribute__((ext_vector_type(8))) short bf16x8;
typedef __attribute__((ext_vector_type(4))) short bf16x4;
typedef __attribute__((ext_vector_type(4))) float f32x4;
typedef __attribute__((ext_vector_type(2))) unsigned int u32x2;

__device__ __forceinline__ void gload_lds16(const void* g, void* l) {
    __builtin_amdgcn_global_load_lds(
        (const __attribute__((address_space(1))) unsigned int*)g,
        (__attribute__((address_space(3))) unsigned int*)l, 16, 0, 0);
}

__device__ __forceinline__ unsigned int pk2(float x, float y) {
    union { __hip_bfloat16 h[2]; unsigned int u; } z;
    z.h[0] = __float2bfloat16(x); z.h[1] = __float2bfloat16(y);
    return z.u;
}

// 16x16x16 bf16 MFMA (HW-verified round 6)
__device__ __forceinline__ f32x4 mfma_16x16x16(bf16x4 a, bf16x4 b, f32x4 c) {
#if __has_builtin(__builtin_amdgcn_mfma_f32_16x16x16bf16_1k)
    return __builtin_amdgcn_mfma_f32_16x16x16bf16_1k(a, b, c, 0, 0, 0);
#else
    f32x4 d = c;
    asm volatile("v_mfma_f32_16x16x16_bf16 %0, %1, %2, %0" : "+v"(d) : "v"(a), "v"(b));
    return d;
#endif
}

// ---------------- fp32 -> bf16 elementwise convert (8 elems/thread) ----------------
__global__ void k_cvt_bf16(const float* __restrict__ x, __hip_bfloat16* __restrict__ o, int n8) {
    int i = blockIdx.x * 256 + threadIdx.x;
    if (i >= n8) return;
    const float4* xp = (const float4*)(x + (size_t)i * 8);
    float4 a = xp[0], b = xp[1];
    union { __hip_bfloat16 h[8]; uint4 u; } tu;
    tu.h[0] = __float2bfloat16(a.x); tu.h[1] = __float2bfloat16(a.y);
    tu.h[2] = __float2bfloat16(a.z); tu.h[3] = __float2bfloat16(a.w);
    tu.h[4] = __float2bfloat16(b.x); tu.h[5] = __float2bfloat16(b.y);
    tu.h[6] = __float2bfloat16(b.z); tu.h[7] = __float2bfloat16(b.w);
    *(uint4*)(o + (size_t)i * 8) = tu.u;
}

// ---------------- transpose fp32 [K][N] -> bf16 [N][K]; z selects one of 3 sources ----------------
__global__ void k_tr3(const float* __restrict__ s0, const float* __restrict__ s1,
                      const float* __restrict__ s2, __hip_bfloat16* __restrict__ dst,
                      int K, int N) {
    __shared__ float tile[32][33];
    const float* src = (blockIdx.z == 0) ? s0 : ((blockIdx.z == 1) ? s1 : s2);
    __hip_bfloat16* d = dst + (size_t)blockIdx.z * N * K;
    int n0 = blockIdx.x * 32, k0 = blockIdx.y * 32;
    int tx = threadIdx.x & 31, ty = threadIdx.x >> 5;
#pragma unroll
    for (int i = 0; i < 4; i++)
        tile[ty + i * 8][tx] = src[(size_t)(k0 + ty + i * 8) * N + n0 + tx];
    __syncthreads();
#pragma unroll
    for (int i = 0; i < 4; i++)
        d[(size_t)(n0 + ty + i * 8) * K + k0 + tx] = __float2bfloat16(tile[tx][ty + i * 8]);
}

__global__ void k_tr(const float* __restrict__ src, __hip_bfloat16* __restrict__ dst, int K, int N) {
    __shared__ float tile[32][33];
    int n0 = blockIdx.x * 32, k0 = blockIdx.y * 32;
    int tx = threadIdx.x & 31, ty = threadIdx.x >> 5;
#pragma unroll
    for (int i = 0; i < 4; i++)
        tile[ty + i * 8][tx] = src[(size_t)(k0 + ty + i * 8) * N + n0 + tx];
    __syncthreads();
#pragma unroll
    for (int i = 0; i < 4; i++)
        dst[(size_t)(n0 + ty + i * 8) * K + k0 + tx] = __float2bfloat16(tile[tx][ty + i * 8]);
}

// ---------------- QKV GEMM (round-9 proven): 128x128 tile, natural 2D grid ----------------
// V path (n0>=2048): in-LDS transpose epilogue, coalesced 16B stores.
#define QSCALE 0.18033688011111204f  /* (1/8) * log2(e) */

__global__ __launch_bounds__(256, 2) void k_gemmQKV(
    const __hip_bfloat16* __restrict__ A, const __hip_bfloat16* __restrict__ Bt, int K,
    const float* __restrict__ b0, const float* __restrict__ b1, const float* __restrict__ b2,
    __hip_bfloat16* __restrict__ qb, __hip_bfloat16* __restrict__ kb, __hip_bfloat16* __restrict__ vb)
{
    __shared__ __align__(16) __hip_bfloat16 Sh[16384];  // As = Sh[0:8192], Bs = Sh[8192:]
    __hip_bfloat16* As = Sh;
    __hip_bfloat16* Bs = Sh + 8192;
    const int t = threadIdx.x;
    const int lane = t & 63, w = t >> 6;
    const int wr = w >> 1, wc = w & 1;
    const int r16 = lane & 15, kg = lane >> 4;
    const int m0 = blockIdx.x * 128, n0 = blockIdx.y * 128;
    f32x4 acc[4][4] = {};
    const int ksteps = K >> 6;
    for (int kt = 0; kt < ksteps; ++kt) {
        if (kt) __syncthreads();
        const int ks = kt * 64;
#pragma unroll
        for (int i2 = 0; i2 < 4; i2++) {
            int ci = i2 * 256 + t;
            int row = ci >> 3, kc = (ci & 7) * 8;
            gload_lds16(A + (size_t)(m0 + row) * K + ks + kc, As + ci * 8);
        }
#pragma unroll
        for (int i2 = 0; i2 < 4; i2++) {
            int ci = i2 * 256 + t;
            int row = ci >> 3, kc = (ci & 7) * 8;
            gload_lds16(Bt + (size_t)(n0 + row) * K + ks + kc, Bs + ci * 8);
        }
        __syncthreads();
#pragma unroll
        for (int c = 0; c < 2; c++) {
            bf16x8 af[4], bfr[4];
#pragma unroll
            for (int mi = 0; mi < 4; mi++)
                af[mi] = *(const bf16x8*)(As + (wr * 64 + mi * 16 + r16) * 64 + c * 32 + kg * 8);
#pragma unroll
            for (int ni = 0; ni < 4; ni++)
                bfr[ni] = *(const bf16x8*)(Bs + (wc * 64 + ni * 16 + r16) * 64 + c * 32 + kg * 8);
#pragma unroll
            for (int mi = 0; mi < 4; mi++)
#pragma unroll
                for (int ni = 0; ni < 4; ni++)
                    acc[mi][ni] = __builtin_amdgcn_mfma_f32_16x16x32_bf16(af[mi], bfr[ni], acc[mi][ni], 0, 0, 0);
        }
    }
    if (n0 >= 2048) {
        // ---- V path: transpose through LDS, coalesced 16B stores ----
        __syncthreads();
#pragma unroll
        for (int mi = 0; mi < 4; mi++) {
#pragma unroll
            for (int ni = 0; ni < 4; ni++) {
                const int nl2 = wc * 64 + ni * 16 + r16;
                const int mb = wr * 64 + mi * 16 + kg * 4;
                const int r = n0 - 2048 + nl2;
                const float bias = b2[r];
                u32x2 pk;
                pk[0] = pk2(acc[mi][ni][0] + bias, acc[mi][ni][1] + bias);
                pk[1] = pk2(acc[mi][ni][2] + bias, acc[mi][ni][3] + bias);
                *(u32x2*)(Sh + nl2 * 128 + (mb ^ ((nl2 & 7) << 3))) = pk;
            }
        }
        __syncthreads();
#pragma unroll
        for (int pass = 0; pass < 8; ++pass) {
            const int ci = pass * 256 + t;
            const int nl2 = ci >> 4;
            const int ms = (ci & 15) * 8;
            bf16x8 v = *(const bf16x8*)(Sh + nl2 * 128 + (ms ^ ((nl2 & 7) << 3)));
            const int r = n0 - 2048 + nl2;
            const int hh = r >> 6, dd = r & 63;
            const int m = m0 + ms;
            const int bb = m >> 11, tt = m & 2047;
            *(bf16x8*)(vb + ((size_t)(bb * 16 + hh) * 64 + dd) * 2048 + tt) = v;
        }
        return;
    }
#pragma unroll
    for (int mi = 0; mi < 4; mi++) {
#pragma unroll
        for (int ni = 0; ni < 4; ni++) {
#pragma unroll
            for (int j = 0; j < 4; j++) {
                int m = m0 + wr * 64 + mi * 16 + kg * 4 + j;
                int n = n0 + wc * 64 + ni * 16 + r16;
                float val = acc[mi][ni][j];
                int r = n & 1023;
                int hh = r >> 6, dd = r & 63;
                int bb = m >> 11, tt = m & 2047;
                if (n < 1024) {
                    val = (val + b0[r]) * QSCALE;
                    qb[((size_t)(bb * 16 + hh) * 2048 + tt) * 64 + dd] = __float2bfloat16(val);
                } else {
                    val += b1[r];
                    kb[((size_t)(bb * 16 + hh) * 2048 + tt) * 64 + dd] = __float2bfloat16(val);
                }
            }
        }
    }
}

// ---------------- proj GEMM: 128x64 tile, 512 blocks -> 4 blocks/CU (was 1/CU at 128x128) ----------
__global__ __launch_bounds__(256, 4) void k_gemmP(
    const __hip_bfloat16* __restrict__ A, const __hip_bfloat16* __restrict__ Bt,
    int N, int K, const float* __restrict__ bias, float* __restrict__ outp)
{
    __shared__ __align__(16) __hip_bfloat16 As[128 * 64];  // 16 KB
    __shared__ __align__(16) __hip_bfloat16 Bs[64 * 64];   //  8 KB
    const int t = threadIdx.x;
    const int lane = t & 63, w = t >> 6;
    const int wr = w >> 1, wc = w & 1;
    const int r16 = lane & 15, kg = lane >> 4;
    const int m0 = blockIdx.x * 128, n0 = blockIdx.y * 64;
    f32x4 acc[4][2] = {};
    const int ksteps = K >> 6;
    for (int kt = 0; kt < ksteps; ++kt) {
        if (kt) __syncthreads();
        const int ks = kt * 64;
#pragma unroll
        for (int i = 0; i < 4; i++) {
            int ci = i * 256 + t;
            int row = ci >> 3, kc = (ci & 7) * 8;
            gload_lds16(A + (size_t)(m0 + row) * K + ks + kc, As + ci * 8);
        }
#pragma unroll
        for (int i = 0; i < 2; i++) {
            int ci = i * 256 + t;
            int row = ci >> 3, kc = (ci & 7) * 8;
            gload_lds16(Bt + (size_t)(n0 + row) * K + ks + kc, Bs + ci * 8);
        }
        __syncthreads();
#pragma unroll
        for (int c = 0; c < 2; c++) {
            bf16x8 af[4], bfr[2];
#pragma unroll
            for (int mi = 0; mi < 4; mi++)
                af[mi] = *(const bf16x8*)(As + (wr * 64 + mi * 16 + r16) * 64 + c * 32 + kg * 8);
#pragma unroll
            for (int ni = 0; ni < 2; ni++)
                bfr[ni] = *(const bf16x8*)(Bs + (wc * 32 + ni * 16 + r16) * 64 + c * 32 + kg * 8);
#pragma unroll
            for (int mi = 0; mi < 4; mi++)
#pragma unroll
                for (int ni = 0; ni < 2; ni++)
                    acc[mi][ni] = __builtin_amdgcn_mfma_f32_16x16x32_bf16(af[mi], bfr[ni], acc[mi][ni], 0, 0, 0);
        }
    }
#pragma unroll
    for (int mi = 0; mi < 4; mi++)
#pragma unroll
        for (int ni = 0; ni < 2; ni++)
#pragma unroll
            for (int j = 0; j < 4; j++) {
                int m = m0 + wr * 64 + mi * 16 + kg * 4 + j;
                int n = n0 + wc * 32 + ni * 16 + r16;
                outp[(size_t)m * N + n] = acc[mi][ni][j] + bias[n];
            }
}

// ---------------- flash attention (round-10 proven): v6 core + bh->XCD remap ----------------
__global__ __launch_bounds__(256, 4) void k_attn(
    const __hip_bfloat16* __restrict__ qbuf,
    const __hip_bfloat16* __restrict__ kbuf,
    const __hip_bfloat16* __restrict__ vtbuf,
    __hip_bfloat16* __restrict__ y)
{
    __shared__ __align__(16) __hip_bfloat16 Kl[2][64 * 64];
    __shared__ __align__(16) __hip_bfloat16 Vl[2][64 * 64];
    const int t = threadIdx.x, lane = t & 63, w = t >> 6;
    const int r16 = lane & 15, kg = lane >> 4;
    const int g = blockIdx.x;
    const int xcd = g & 7, idx = g >> 3;
    const int j4 = idx >> 5, rr = idx & 31;
    const int bh = xcd * 4 + j4;
    const int qt = (j4 & 1) ? rr : 31 - rr;
    const int swr = (r16 & 7) << 3;
    const int q0 = qt * 64 + w * 16;
    const __hip_bfloat16* qp = qbuf + ((size_t)bh * 2048 + q0) * 64;
    bf16x8 qf0 = *(const bf16x8*)(qp + r16 * 64 + kg * 8);
    bf16x8 qf1 = *(const bf16x8*)(qp + r16 * 64 + 32 + kg * 8);
    f32x4 O[4] = {};
    float m_s = -3.0e38f, l_s = 0.f;
    const __hip_bfloat16* kb = kbuf + (size_t)bh * 2048 * 64;
    const __hip_bfloat16* vb = vtbuf + (size_t)bh * 64 * 2048;

    const int ci0 = t, ci1 = 256 + t;
    const int kr0 = ci0 >> 3, sc0 = ((ci0 & 7) * 8) ^ ((kr0 & 7) << 3);
    const int kr1 = ci1 >> 3, sc1 = ((ci1 & 7) * 8) ^ ((kr1 & 7) << 3);

    gload_lds16(kb + (size_t)kr0 * 64 + sc0, &Kl[0][ci0 * 8]);
    gload_lds16(kb + (size_t)kr1 * 64 + sc1, &Kl[0][ci1 * 8]);
    gload_lds16(vb + (size_t)kr0 * 2048 + sc0, &Vl[0][ci0 * 8]);
    gload_lds16(vb + (size_t)kr1 * 2048 + sc1, &Vl[0][ci1 * 8]);
    __syncthreads();

    for (int kt = 0; kt <= qt; ++kt) {
        const int cur = kt & 1;
        if (kt < qt) {
            const int kn = kt + 1;
            gload_lds16(kb + (size_t)kn * 4096 + (size_t)kr0 * 64 + sc0, &Kl[cur ^ 1][ci0 * 8]);
            gload_lds16(kb + (size_t)kn * 4096 + (size_t)kr1 * 64 + sc1, &Kl[cur ^ 1][ci1 * 8]);
            gload_lds16(vb + (size_t)kr0 * 2048 + kn * 64 + sc0, &Vl[cur ^ 1][ci0 * 8]);
            gload_lds16(vb + (size_t)kr1 * 2048 + kn * 64 + sc1, &Vl[cur ^ 1][ci1 * 8]);
        }
        const int kbase = kt * 64;
        {
            const __hip_bfloat16* Klb = Kl[cur];
            const __hip_bfloat16* Vlb = Vl[cur];
            f32x4 S[4];
            __builtin_amdgcn_s_setprio(1);
#pragma unroll
            for (int ct = 0; ct < 4; ct++) {
                f32x4 s = {};
                const int r = ct * 16 + r16;
                bf16x8 kf0 = *(const bf16x8*)(Klb + r * 64 + ((kg * 8) ^ swr));
                s = __builtin_amdgcn_mfma_f32_16x16x32_bf16(kf0, qf0, s, 0, 0, 0);
                bf16x8 kf1 = *(const bf16x8*)(Klb + r * 64 + ((32 + kg * 8) ^ swr));
                s = __builtin_amdgcn_mfma_f32_16x16x32_bf16(kf1, qf1, s, 0, 0, 0);
                S[ct] = s;
            }
            __builtin_amdgcn_s_setprio(0);
            if (kbase + 63 > q0) {
#pragma unroll
                for (int ct = 0; ct < 4; ct++)
#pragma unroll
                    for (int j = 0; j < 4; j++)
                        if (kbase + ct * 16 + kg * 4 + j > q0 + r16) S[ct][j] = -3.0e38f;
            }
            float rmax = S[0][0];
#pragma unroll
            for (int ct = 0; ct < 4; ct++)
#pragma unroll
                for (int j = 0; j < 4; j++) rmax = fmaxf(rmax, S[ct][j]);
            rmax = fmaxf(rmax, __shfl_xor(rmax, 16));
            rmax = fmaxf(rmax, __shfl_xor(rmax, 32));
            if (__any(rmax > m_s + 8.0f)) {
                const float mn = fmaxf(m_s, rmax);
                const float al = exp2f(m_s - mn);
                m_s = mn;
                l_s *= al;
#pragma unroll
                for (int j = 0; j < 4; j++) {
                    const float aj = __shfl(al, kg * 4 + j);
#pragma unroll
                    for (int ot = 0; ot < 4; ot++) O[ot][j] *= aj;
                }
            }
            float rsum = 0.f;
#pragma unroll
            for (int ct = 0; ct < 4; ct++)
#pragma unroll
                for (int j = 0; j < 4; j++) { S[ct][j] = exp2f(S[ct][j] - m_s); rsum += S[ct][j]; }
            rsum += __shfl_xor(rsum, 16);
            rsum += __shfl_xor(rsum, 32);
            l_s += rsum;
            bf16x4 pa[4];
#pragma unroll
            for (int ct = 0; ct < 4; ct++) {
                union { __hip_bfloat16 h[4]; bf16x4 v; } pk;
                pk.h[0] = __float2bfloat16(S[ct][0]);
                pk.h[1] = __float2bfloat16(S[ct][1]);
                pk.h[2] = __float2bfloat16(S[ct][2]);
                pk.h[3] = __float2bfloat16(S[ct][3]);
                pa[ct] = pk.v;
            }
            __builtin_amdgcn_s_setprio(1);
#pragma unroll
            for (int ot = 0; ot < 4; ot++) {
                const int vrow = ot * 16 + r16;
#pragma unroll
                for (int ct = 0; ct < 4; ct++) {
                    bf16x4 vf = *(const bf16x4*)(Vlb + vrow * 64 + ((ct * 16 + kg * 4) ^ ((vrow & 7) << 3)));
                    O[ot] = mfma_16x16x16(pa[ct], vf, O[ot]);
                }
            }
            __builtin_amdgcn_s_setprio(0);
        }
        __syncthreads();
    }
    const int b = bh >> 4, h = bh & 15;
    const float linv = 1.0f / l_s;
#pragma unroll
    for (int j = 0; j < 4; j++) {
        const float iv = __shfl(linv, kg * 4 + j);
        const int qq = q0 + kg * 4 + j;
#pragma unroll
        for (int ot = 0; ot < 4; ot++)
            y[((size_t)b * 2048 + qq) * 1024 + h * 64 + ot * 16 + r16] = __float2bfloat16(O[ot][j] * iv);
    }
}

extern "C" void kernel_launch(void* const* d_in, const int* in_sizes, int n_in,
                              void* d_out, int out_size, void* d_ws, size_t ws_size,
                              hipStream_t stream) {
    const float* xp = (const float*)d_in[0];
    const float* Wq = (const float*)d_in[1];
    const float* bq = (const float*)d_in[2];
    const float* Wk = (const float*)d_in[3];
    const float* bk = (const float*)d_in[4];
    const float* Wv = (const float*)d_in[5];
    const float* bv = (const float*)d_in[6];
    const float* Wp = (const float*)d_in[7];
    const float* bp = (const float*)d_in[8];
    float* out = (float*)d_out;

    char* ws = (char*)d_ws;
    __hip_bfloat16* xb     = (__hip_bfloat16*)(ws);                  //  4096*1152 bf16
    __hip_bfloat16* Wqkv_t = (__hip_bfloat16*)(ws + 9437184);        //  3072*1152 bf16 (B^T)
    __hip_bfloat16* Wp_t   = (__hip_bfloat16*)(ws + 16515072);       //  1024*1024 bf16 (B^T)
    __hip_bfloat16* qb     = (__hip_bfloat16*)(ws + 18612224);       //  [32][2048][64]
    __hip_bfloat16* kbv    = (__hip_bfloat16*)(ws + 27000832);       //  [32][2048][64]
    __hip_bfloat16* vtb    = (__hip_bfloat16*)(ws + 35389440);       //  [32][64][2048] (V^T)
    __hip_bfloat16* yb     = (__hip_bfloat16*)(ws + 43778048);       //  [4096][1024]

    k_cvt_bf16<<<2304, 256, 0, stream>>>(xp, xb, 589824);
    dim3 trg3(1024 / 32, 1152 / 32, 3);
    k_tr3<<<trg3, 256, 0, stream>>>(Wq, Wk, Wv, Wqkv_t, 1152, 1024);
    dim3 trg2(1024 / 32, 1024 / 32);
    k_tr<<<trg2, 256, 0, stream>>>(Wp, Wp_t, 1024, 1024);

    dim3 g1(4096 / 128, 3072 / 128);
    k_gemmQKV<<<g1, 256, 0, stream>>>(xb, Wqkv_t, 1152, bq, bk, bv, qb, kbv, vtb);
    k_attn<<<1024, 256, 0, stream>>>(qb, kbv, vtb, yb);
    dim3 gp(4096 / 128, 1024 / 64);
    k_gemmP<<<gp, 256, 0, stream>>>(yb, Wp_t, 1024, 1024, bp, out);
}